// Round 1
// baseline (530.468 us; speedup 1.0000x reference)
//
#include <hip/hip_runtime.h>
#include <hip/hip_bf16.h>

namespace {
constexpr int NPTS  = 65536;   // points per batch
constexpr int KNB   = 16;      // neighbors
constexpr int CMID  = 16;
constexpr int CIN   = 64;
constexpr int CADD  = 3;
constexpr int COUT  = 128;
constexpr int KREAL = 1072;    // 67*16
constexpr int KPAD  = 1088;    // 68*16 (c padded to 68)
constexpr int MT    = 32;      // points per block
constexpr int PSTR  = 1096;    // LDS row stride for pconv (+8 pad: breaks bank conflicts)
constexpr int WSTR  = 40;      // LDS row stride for W tile (32 + 8 pad)
}

typedef __attribute__((ext_vector_type(8))) __bf16 bf16x8;
typedef __attribute__((ext_vector_type(4))) float f32x4;

__device__ __forceinline__ unsigned int pack_bf2(float a, float b) {
  __hip_bfloat162 h = __float22bfloat162_rn(make_float2(a, b));
  return *reinterpret_cast<unsigned int*>(&h);
}

// One-time: W [128][1072] f32 -> bf16 zero-padded to [128][1088] in workspace.
__global__ void convert_w(const float* __restrict__ W, unsigned short* __restrict__ Wb) {
  const int o = blockIdx.x;
  for (int k = threadIdx.x; k < KPAD; k += blockDim.x) {
    float v = (k < KREAL) ? W[o * KREAL + k] : 0.0f;
    __hip_bfloat16 h = __float2bfloat16(v);
    Wb[o * KPAD + k] = *reinterpret_cast<unsigned short*>(&h);
  }
}

__global__ __launch_bounds__(256, 2) void pconv_fused(
    const float* __restrict__ feat,        // [2][65536][64]
    const int* __restrict__ nidx,          // [2][65536][16]
    const float* __restrict__ wn,          // [2][65536][16][16]
    const float* __restrict__ addf,        // [2][65536][16][3]
    const float* __restrict__ W,           // [128][1072]
    const float* __restrict__ bias,        // [128]
    const unsigned short* __restrict__ Wb, // [128][1088] bf16 (optional)
    int useWb,
    float* __restrict__ out)               // [2][65536][128]
{
  __shared__ unsigned short s_p[MT * PSTR];   // pconv tile, bf16 bits
  __shared__ unsigned short s_w[COUT * WSTR]; // W k-slab, bf16 bits [o][k]

  const int tid = threadIdx.x;

  // ---------------- stage 1: pconv -> LDS (bf16) ----------------
  {
    const int p  = tid >> 3;     // point within block
    const int jp = tid & 7;      // j-pair: handles j = 2*jp, 2*jp+1
    const int mg = blockIdx.x * MT + p;
    const int b  = mg >> 16;
    const float* fb  = feat + (size_t)b * (NPTS * CIN);
    const int*   ni  = nidx + (size_t)mg * KNB;
    const float* wnp = wn   + (size_t)mg * (KNB * CMID) + jp * 2;
    const float* ap  = addf + (size_t)mg * (KNB * CADD);

    float2 acc[68];
#pragma unroll
    for (int c = 0; c < 68; ++c) acc[c] = make_float2(0.f, 0.f);

    for (int k = 0; k < KNB; ++k) {
      const int nb = ni[k];
      const float4* row = reinterpret_cast<const float4*>(fb + (size_t)nb * CIN);
      const float2 w = *reinterpret_cast<const float2*>(wnp + k * CMID);
#pragma unroll
      for (int cc = 0; cc < 16; ++cc) {
        const float4 f = row[cc];
        acc[cc*4+0].x = fmaf(f.x, w.x, acc[cc*4+0].x);
        acc[cc*4+0].y = fmaf(f.x, w.y, acc[cc*4+0].y);
        acc[cc*4+1].x = fmaf(f.y, w.x, acc[cc*4+1].x);
        acc[cc*4+1].y = fmaf(f.y, w.y, acc[cc*4+1].y);
        acc[cc*4+2].x = fmaf(f.z, w.x, acc[cc*4+2].x);
        acc[cc*4+2].y = fmaf(f.z, w.y, acc[cc*4+2].y);
        acc[cc*4+3].x = fmaf(f.w, w.x, acc[cc*4+3].x);
        acc[cc*4+3].y = fmaf(f.w, w.y, acc[cc*4+3].y);
      }
      const float a0 = ap[k*3+0], a1 = ap[k*3+1], a2 = ap[k*3+2];
      acc[64].x = fmaf(a0, w.x, acc[64].x);
      acc[64].y = fmaf(a0, w.y, acc[64].y);
      acc[65].x = fmaf(a1, w.x, acc[65].x);
      acc[65].y = fmaf(a1, w.y, acc[65].y);
      acc[66].x = fmaf(a2, w.x, acc[66].x);
      acc[66].y = fmaf(a2, w.y, acc[66].y);
      // acc[67] stays zero (pad channel)
    }

    unsigned short* dst = s_p + p * PSTR + jp * 2;
#pragma unroll
    for (int c = 0; c < 68; ++c) {
      *reinterpret_cast<unsigned int*>(dst + c * 16) = pack_bf2(acc[c].x, acc[c].y);
    }
  }

  // ---------------- stage 2: out[32][128] = pconv[32][1088] @ Wb^T ----------------
  const int wid   = tid >> 6;
  const int lane  = tid & 63;
  const int quad  = lane >> 4;
  const int l     = lane & 15;
  const int mtile = wid & 1;          // waves 0,2 -> mtile 0; 1,3 -> mtile 1
  const int nbase = (wid >> 1) * 64;  // output-channel base (4 n-tiles per wave)

  f32x4 acc2[4];
#pragma unroll
  for (int nt = 0; nt < 4; ++nt) acc2[nt] = (f32x4){0.f, 0.f, 0.f, 0.f};

  const int o    = tid >> 1;   // staging: output channel
  const int half = tid & 1;    // staging: which 16-element half of the 32-k slab

  for (int kt = 0; kt < KPAD / 32; ++kt) {   // 34 iterations
    __syncthreads();
    {
      const int kb = kt * 32 + half * 16;
      uint4 v0, v1;
      if (useWb) {
        const uint4* src = reinterpret_cast<const uint4*>(Wb + (size_t)o * KPAD + kb);
        v0 = src[0]; v1 = src[1];
      } else {
        if (kb < KREAL) {
          const float4* src = reinterpret_cast<const float4*>(W + (size_t)o * KREAL + kb);
          const float4 f0 = src[0], f1 = src[1], f2 = src[2], f3 = src[3];
          v0.x = pack_bf2(f0.x, f0.y); v0.y = pack_bf2(f0.z, f0.w);
          v0.z = pack_bf2(f1.x, f1.y); v0.w = pack_bf2(f1.z, f1.w);
          v1.x = pack_bf2(f2.x, f2.y); v1.y = pack_bf2(f2.z, f2.w);
          v1.z = pack_bf2(f3.x, f3.y); v1.w = pack_bf2(f3.z, f3.w);
        } else {
          v0 = make_uint4(0, 0, 0, 0);
          v1 = make_uint4(0, 0, 0, 0);
        }
      }
      uint4* d = reinterpret_cast<uint4*>(s_w + o * WSTR + half * 16);
      d[0] = v0; d[1] = v1;
    }
    __syncthreads();

    // A frag: A[m = l][k = quad*8 + j]
    const bf16x8 a = *reinterpret_cast<const bf16x8*>(
        s_p + (mtile * 16 + l) * PSTR + kt * 32 + quad * 8);
#pragma unroll
    for (int nt = 0; nt < 4; ++nt) {
      // B frag: B[k = quad*8 + j][n = l] == W[n][k]
      const bf16x8 bb = *reinterpret_cast<const bf16x8*>(
          s_w + (nbase + nt * 16 + l) * WSTR + quad * 8);
      acc2[nt] = __builtin_amdgcn_mfma_f32_16x16x32_bf16(a, bb, acc2[nt], 0, 0, 0);
    }
  }

  // epilogue: C/D layout col=lane&15, row=quad*4+reg
  const int mrow = blockIdx.x * MT + mtile * 16 + quad * 4;
#pragma unroll
  for (int nt = 0; nt < 4; ++nt) {
    const int oc = nbase + nt * 16 + l;
    const float bv = bias[oc];
#pragma unroll
    for (int r = 0; r < 4; ++r) {
      out[(size_t)(mrow + r) * COUT + oc] = acc2[nt][r] + bv;
    }
  }
}

extern "C" void kernel_launch(void* const* d_in, const int* in_sizes, int n_in,
                              void* d_out, int out_size, void* d_ws, size_t ws_size,
                              hipStream_t stream) {
  const float* feat = (const float*)d_in[0];
  const int*   nidx = (const int*)d_in[1];
  const float* wn   = (const float*)d_in[2];
  const float* addf = (const float*)d_in[3];
  const float* W    = (const float*)d_in[4];
  const float* bias = (const float*)d_in[5];
  float* out = (float*)d_out;

  unsigned short* Wb = (unsigned short*)d_ws;
  const int useWb = (ws_size >= (size_t)COUT * KPAD * 2) ? 1 : 0;
  if (useWb) {
    convert_w<<<COUT, 256, 0, stream>>>(W, Wb);
  }
  const int nblocks = (2 * NPTS) / MT;  // 4096
  pconv_fused<<<nblocks, 256, 0, stream>>>(feat, nidx, wn, addf, W, bias, Wb, useWb, out);
}